// Round 3
// baseline (2742.329 us; speedup 1.0000x reference)
//
#include <hip/hip_runtime.h>
#include <hip/hip_bf16.h>
#include <stdint.h>

// MultilayerPCN: predictive-coding inference loop, bf16-MFMA + split-K version.
// NODES = [2048, 4096, 8192], B = 256, n_iters = 8 (hardcoded), LAMB = 0.5.
// Output: 8 fp32 energies.
//
// R2 diagnosis: MfmaUtil 4.7%, Occupancy 6% -> latency-bound (192/384-block
// grids = ~1 wave/SIMD, barrier drain fully exposed). Fix: split-K.
//
// Per iteration, 2 GEMM phases + 4 tiny epilogue kernels:
//   phase1: [G2 = e2@W1 (split 4)  ||  G1 = e1@W0 (split 2)]   -> fp32 partials
//           EpiG2: v1 update + T1b;  EpiG1: v0 update + T0b + loss(ne0)
//   phase2: [G4 = T1@W1^T (split 2) || G3 = T0@W0^T (split 2)] -> fp32 partials
//           EpiG4: e2b + loss(ne2);  EpiG3: e1/e1b + loss(ne1)
//
// GEMM: BM=128, BN=64, BK=32; 256 thr (4 waves 2x2, wave 64x32, 4x2 mfma);
// global_load_lds width-16 staging; mfma_f32_16x16x32_bf16; fp32 partial store.
// Grids: 640 (phase1) / 768 (phase2) blocks -> ~3 blocks/CU, 12 waves/CU.
// Weights cast per-call to bf16 in both orientations (B^T always N x K).
// ws use ~190 MB (165 + 24 MB partials).

typedef short short8x __attribute__((ext_vector_type(8)));
typedef float float4x __attribute__((ext_vector_type(4)));
typedef unsigned short u16;
typedef u16 u16x4 __attribute__((ext_vector_type(4)));

static constexpr float LOSS_SCALE = 100.0f / 256.0f;

__device__ __forceinline__ u16 f2b(float x) {
    union { float f; uint32_t u; } v{x};
    uint32_t b = v.u + 0x7fffu + ((v.u >> 16) & 1u);
    return (u16)(b >> 16);
}

__device__ __forceinline__ float signf_(float x) {
    return (x > 0.f) ? 1.f : ((x < 0.f) ? -1.f : 0.f);
}

__device__ __forceinline__ void gload_lds16(const void* g, void* lds) {
    __builtin_amdgcn_global_load_lds(
        (const __attribute__((address_space(1))) void*)g,
        (__attribute__((address_space(3))) void*)lds, 16, 0, 0);
}

// ---------------- init / cast kernels ----------------
__global__ void k_zero(float* p, int n) {
    int i = blockIdx.x * blockDim.x + threadIdx.x;
    if (i < n) p[i] = 0.f;
}

__global__ void k_cast(const float* __restrict__ in, u16* __restrict__ out, int n) {
    int i = blockIdx.x * blockDim.x + threadIdx.x;
    if (i < n) out[i] = f2b(in[i]);
}

// out (C x R bf16) = transpose(in (R x C f32))
__global__ __launch_bounds__(256) void k_transpose_cast(
    const float* __restrict__ in, u16* __restrict__ out, int R, int C) {
    __shared__ float tile[32][33];
    int x = blockIdx.x * 32 + threadIdx.x;
#pragma unroll
    for (int k = 0; k < 32; k += 8) {
        int y = blockIdx.y * 32 + threadIdx.y + k;
        tile[threadIdx.y + k][threadIdx.x] = in[(size_t)y * C + x];
    }
    __syncthreads();
    int ox = blockIdx.y * 32 + threadIdx.x;
#pragma unroll
    for (int k = 0; k < 32; k += 8) {
        int oy = blockIdx.x * 32 + threadIdx.y + k;
        out[(size_t)oy * R + ox] = f2b(tile[threadIdx.x][threadIdx.y + k]);
    }
}

__global__ void k_fill_v0(float* __restrict__ v0, const float* __restrict__ memory,
                          int n, int mask) {
    int i = blockIdx.x * blockDim.x + threadIdx.x;
    if (i < n) v0[i] = memory[i & mask];
}

__global__ void k_tanh(float* __restrict__ dst, const float* __restrict__ src, int n) {
    int i = blockIdx.x * blockDim.x + threadIdx.x;
    if (i < n) dst[i] = tanhf(src[i]);
}

// out[i] = sum_j x[j] * W[i*K + j]  (fp32, one block per row; init only)
__global__ void k_rowdot(const float* __restrict__ x, const float* __restrict__ W,
                         float* __restrict__ out, int K) {
    int i = blockIdx.x;
    const float* w = W + (size_t)i * K;
    float s = 0.f;
    for (int j = threadIdx.x; j < K; j += 256) s += x[j] * w[j];
    __shared__ float red[256];
    red[threadIdx.x] = s;
    __syncthreads();
    for (int st = 128; st > 0; st >>= 1) {
        if (threadIdx.x < st) red[threadIdx.x] += red[threadIdx.x + st];
        __syncthreads();
    }
    if (threadIdx.x == 0) out[i] = red[0];
}

__global__ void k_bcast_v1_e1(float* __restrict__ v1, float* __restrict__ e1,
                              u16* __restrict__ e1b,
                              const float* __restrict__ r1, int n, int mask) {
    int i = blockIdx.x * blockDim.x + threadIdx.x;
    if (i < n) { v1[i] = r1[i & mask]; e1[i] = 0.f; e1b[i] = 0; }
}

__global__ void k_e2_init(u16* __restrict__ e2b, const float* __restrict__ inp,
                          const float* __restrict__ r2, int n, int mask) {
    int i = blockIdx.x * blockDim.x + threadIdx.x;
    if (i < n) e2b[i] = f2b(inp[i] - r2[i & mask]);
}

// ---------------- split-K MFMA GEMM (partial-C producer) ----------------
struct GD {
    const u16* A;    // [256, K] bf16 row-major
    const u16* Bt;   // [N, K]  bf16 row-major (B transposed)
    float* Cp;       // partials; split s at Cp + s*256*N
    int N, K;        // K = full K (row stride of A/Bt)
    int nCol;        // N/64
    int Ksp;         // K per split
    int nBlocks;     // 2 * nCol * nSplit
};

__global__ __launch_bounds__(256) void pcn_gemm(GD ga, GD gb, int nA) {
    __shared__ u16 As[4096];   // 128x32, 8 KB
    __shared__ u16 Bs[2048];   // 64x32, 4 KB

    int bx = blockIdx.x;
    GD g = (bx < nA) ? ga : gb;
    if (bx >= nA) bx -= nA;
    const int tilesPerSplit = 2 * g.nCol;
    const int split = bx / tilesPerSplit;
    const int rc = bx - split * tilesPerSplit;
    const int rowBlk = rc / g.nCol, colBlk = rc - rowBlk * g.nCol;

    const int t = threadIdx.x;
    const int w = t >> 6, l = t & 63;
    const int row0 = rowBlk * 128, col0 = colBlk * 64;
    const int K = g.K;
    const int kBeg = split * g.Ksp;

    // staging: per-thread 16B contiguous; A 8KB (2 issues), B 4KB (1 issue)
    const int srow = t >> 2;                 // 0..63
    const int scolE = (t & 3) << 3;          // 0/8/16/24 elements
    const u16* aptr0 = g.A + (size_t)(row0 + srow) * K + kBeg + scolE;
    const u16* aptr1 = g.A + (size_t)(row0 + 64 + srow) * K + kBeg + scolE;
    const u16* bptr  = g.Bt + (size_t)(col0 + srow) * K + kBeg + scolE;
    u16* alds0 = As + (w << 9);
    u16* alds1 = As + 2048 + (w << 9);
    u16* blds  = Bs + (w << 9);

    const int wm = (w >> 1) << 6;            // 0 / 64
    const int wn = (w & 1) << 5;             // 0 / 32
    const int lm = l & 15, lq = l >> 4;

    int aoff[4], boff[2];
#pragma unroll
    for (int i = 0; i < 4; ++i) aoff[i] = (wm + i * 16 + lm) * 32 + lq * 8;
#pragma unroll
    for (int j = 0; j < 2; ++j) boff[j] = (wn + j * 16 + lm) * 32 + lq * 8;

    float4x acc[4][2];
#pragma unroll
    for (int i = 0; i < 4; ++i)
#pragma unroll
        for (int j = 0; j < 2; ++j) acc[i][j] = (float4x)0.f;

    for (int k0 = 0; k0 < g.Ksp; k0 += 32) {
        gload_lds16(aptr0 + k0, alds0);
        gload_lds16(aptr1 + k0, alds1);
        gload_lds16(bptr + k0, blds);
        __syncthreads();
        short8x a[4], b[2];
#pragma unroll
        for (int i = 0; i < 4; ++i) a[i] = *(const short8x*)(As + aoff[i]);
#pragma unroll
        for (int j = 0; j < 2; ++j) b[j] = *(const short8x*)(Bs + boff[j]);
#pragma unroll
        for (int i = 0; i < 4; ++i)
#pragma unroll
            for (int j = 0; j < 2; ++j)
                acc[i][j] = __builtin_amdgcn_mfma_f32_16x16x32_bf16(a[i], b[j], acc[i][j], 0, 0, 0);
        __syncthreads();
    }

    // store fp32 partial C  (C/D layout: col = lane&15, row = (lane>>4)*4 + reg)
    float* C = g.Cp + (size_t)split * ((size_t)256 * g.N);
#pragma unroll
    for (int i = 0; i < 4; ++i)
#pragma unroll
        for (int j = 0; j < 2; ++j)
#pragma unroll
            for (int r = 0; r < 4; ++r) {
                const int m = row0 + wm + i * 16 + lq * 4 + r;
                const int n = col0 + wn + j * 16 + lm;
                C[(size_t)m * g.N + n] = acc[i][j][r];
            }
}

// ---------------- fused split-sum + node-update epilogues ----------------
// EPI1: v0 update, T0b, loss(ne0).  EPI2: v1 update, T1b.
// EPI3: e1 = v1 - c (f32 + bf16), loss.  EPI4: e2b = inp - c, loss.
template <int NS, int EPI>
__global__ __launch_bounds__(256) void pcn_epi(
    const float* __restrict__ Cp, const float* __restrict__ x0,
    const float* __restrict__ x1, float* __restrict__ y0,
    u16* __restrict__ y0b, u16* __restrict__ y1b,
    float* __restrict__ loss, const float* __restrict__ lr_ptr,
    int n, int mask)
{
    const int i = (blockIdx.x * 256 + threadIdx.x) * 4;
    float4x c = *(const float4x*)(Cp + i);
#pragma unroll
    for (int s = 1; s < NS; ++s) {
        float4x cs = *(const float4x*)(Cp + (size_t)s * n + i);
        c += cs;
    }

    float lr = 0.f;
    if (EPI == 1 || EPI == 2) lr = *lr_ptr;
    float lsum = 0.f;

    if (EPI == 1) {
        float4x v = *(const float4x*)(x0 + i);
        float4x mem = *(const float4x*)(x1 + (i & mask));
        float4x nvv; u16x4 tb;
#pragma unroll
        for (int r = 0; r < 4; ++r) {
            float vv = v[r], th = tanhf(vv), td = 1.f - th * th;
            float d0 = (mem[r] - vv) - 0.5f * signf_(vv) + td * c[r];
            float nv = vv + lr * d0;
            nv = nv > 0.f ? nv : 0.f;
            nvv[r] = nv;
            tb[r] = f2b(tanhf(nv));
            float ne0 = nv - mem[r];
            lsum += ne0 * ne0;
        }
        *(float4x*)(y0 + i) = nvv;
        *(u16x4*)(y1b + i) = tb;
    } else if (EPI == 2) {
        float4x v = *(const float4x*)(x0 + i);
        float4x e1v = *(const float4x*)(x1 + i);
        float4x nvv; u16x4 tb;
#pragma unroll
        for (int r = 0; r < 4; ++r) {
            float vv = v[r], th = tanhf(vv), td = 1.f - th * th;
            float nv = vv + lr * (-e1v[r] + td * c[r]);
            nv = nv > 0.f ? nv : 0.f;
            nvv[r] = nv;
            tb[r] = f2b(tanhf(nv));
        }
        *(float4x*)(y0 + i) = nvv;
        *(u16x4*)(y1b + i) = tb;
    } else if (EPI == 3) {
        float4x v = *(const float4x*)(x0 + i);
        float4x ne; u16x4 nb;
#pragma unroll
        for (int r = 0; r < 4; ++r) {
            float e = v[r] - c[r];
            ne[r] = e; nb[r] = f2b(e);
            lsum += e * e;
        }
        *(float4x*)(y0 + i) = ne;
        *(u16x4*)(y0b + i) = nb;
    } else {
        float4x v = *(const float4x*)(x0 + i);
        u16x4 nb;
#pragma unroll
        for (int r = 0; r < 4; ++r) {
            float e = v[r] - c[r];
            nb[r] = f2b(e);
            lsum += e * e;
        }
        *(u16x4*)(y1b + i) = nb;
    }

    if (EPI != 2) {
#pragma unroll
        for (int off = 32; off > 0; off >>= 1) lsum += __shfl_down(lsum, off);
        if ((threadIdx.x & 63) == 0) atomicAdd(loss, lsum * LOSS_SCALE);
    }
}

extern "C" void kernel_launch(void* const* d_in, const int* in_sizes, int n_in,
                              void* d_out, int out_size, void* d_ws, size_t ws_size,
                              hipStream_t stream)
{
    const float* batch_inp = (const float*)d_in[0]; // (256, 8192)
    const float* W0        = (const float*)d_in[1]; // (4096, 2048)
    const float* W1        = (const float*)d_in[2]; // (8192, 4096)
    const float* memory    = (const float*)d_in[3]; // (2048,)
    const float* lr_ptr    = (const float*)d_in[5]; // 0.05
    float* out = (float*)d_out;                     // 8 losses

    const int n0 = 2048, n1 = 4096, n2 = 8192, Bn = 256;

    // ---- workspace layout ----
    char* ws = (char*)d_ws;
    auto alloc_f = [&](size_t n) { float* p = (float*)ws; ws += n * 4; return p; };
    auto alloc_b = [&](size_t n) { u16* p = (u16*)ws; ws += n * 2; return p; };

    float* v0  = alloc_f((size_t)Bn * n0);
    float* v1  = alloc_f((size_t)Bn * n1);
    float* e1  = alloc_f((size_t)Bn * n1);
    u16*   e1b = alloc_b((size_t)Bn * n1);
    u16*   e2b = alloc_b((size_t)Bn * n2);
    u16*   T0b = alloc_b((size_t)Bn * n0);
    u16*   T1b = alloc_b((size_t)Bn * n1);
    u16*   W0b  = alloc_b((size_t)n1 * n0);   // (n1, n0)
    u16*   W0Tb = alloc_b((size_t)n0 * n1);   // (n0, n1)
    u16*   W1b  = alloc_b((size_t)n2 * n1);   // (n2, n1)
    u16*   W1Tb = alloc_b((size_t)n1 * n2);   // (n1, n2)
    float* CpBig   = alloc_f((size_t)4 * Bn * n1);  // 16 MB: G2 x4 / G4 x2
    float* CpSmall = alloc_f((size_t)2 * Bn * n1);  //  8 MB: G1 x2 / G3 x2
    float* tm = alloc_f(n0);
    float* r1 = alloc_f(n1);
    float* t1 = alloc_f(n1);
    float* r2 = alloc_f(n2);

    // ---- one-time init ----
    k_zero<<<1, 32, 0, stream>>>(out, 8);
    k_cast<<<(n1 * n0) / 256, 256, 0, stream>>>(W0, W0b, n1 * n0);
    k_cast<<<(n2 * n1) / 256, 256, 0, stream>>>(W1, W1b, n2 * n1);
    k_transpose_cast<<<dim3(n0 / 32, n1 / 32), dim3(32, 8), 0, stream>>>(W0, W0Tb, n1, n0);
    k_transpose_cast<<<dim3(n1 / 32, n2 / 32), dim3(32, 8), 0, stream>>>(W1, W1Tb, n2, n1);
    k_fill_v0<<<(Bn * n0) / 256, 256, 0, stream>>>(v0, memory, Bn * n0, n0 - 1);
    k_tanh<<<n0 / 256, 256, 0, stream>>>(tm, memory, n0);
    k_rowdot<<<n1, 256, 0, stream>>>(tm, W0, r1, n0);        // r1 = tanh(mem) @ W0^T
    k_tanh<<<n1 / 256, 256, 0, stream>>>(t1, r1, n1);
    k_bcast_v1_e1<<<(Bn * n1) / 256, 256, 0, stream>>>(v1, e1, e1b, r1, Bn * n1, n1 - 1);
    k_rowdot<<<n2, 256, 0, stream>>>(t1, W1, r2, n1);        // r2 = tanh(r1) @ W1^T
    k_e2_init<<<(Bn * n2) / 256, 256, 0, stream>>>(e2b, batch_inp, r2, Bn * n2, n2 - 1);

    // ---- 8 inference iterations ----
    for (int it = 0; it < 8; ++it) {
        float* loss = out + it;

        // phase 1: G2 (K=8192, split 4) || G1 (K=4096, split 2) — 640 blocks
        GD g2{e2b, W1Tb, CpBig,   n1, n2, n1 / 64, n2 / 4, 2 * (n1 / 64) * 4};
        GD g1{e1b, W0Tb, CpSmall, n0, n1, n0 / 64, n1 / 2, 2 * (n0 / 64) * 2};
        pcn_gemm<<<g2.nBlocks + g1.nBlocks, 256, 0, stream>>>(g2, g1, g2.nBlocks);
        pcn_epi<4, 2><<<(Bn * n1) / 1024, 256, 0, stream>>>(
            CpBig, v1, e1, v1, nullptr, T1b, nullptr, lr_ptr, Bn * n1, 0);
        pcn_epi<2, 1><<<(Bn * n0) / 1024, 256, 0, stream>>>(
            CpSmall, v0, memory, v0, nullptr, T0b, loss, lr_ptr, Bn * n0, n0 - 1);

        // phase 2: G4 (K=4096, split 2) || G3 (K=2048, split 2) — 768 blocks
        GD g4{T1b, W1b, CpBig,   n2, n1, n2 / 64, n1 / 2, 2 * (n2 / 64) * 2};
        GD g3{T0b, W0b, CpSmall, n1, n0, n1 / 64, n0 / 2, 2 * (n1 / 64) * 2};
        pcn_gemm<<<g4.nBlocks + g3.nBlocks, 256, 0, stream>>>(g4, g3, g4.nBlocks);
        pcn_epi<2, 4><<<(Bn * n2) / 1024, 256, 0, stream>>>(
            CpBig, batch_inp, nullptr, nullptr, nullptr, e2b, loss, nullptr, Bn * n2, 0);
        pcn_epi<2, 3><<<(Bn * n1) / 1024, 256, 0, stream>>>(
            CpSmall, v1, nullptr, e1, e1b, nullptr, loss, nullptr, Bn * n1, 0);
    }
}